// Round 1
// baseline (4080.176 us; speedup 1.0000x reference)
//
#include <hip/hip_runtime.h>
#include <stdint.h>

// Problem constants
#define B_   64
#define T_   512
#define E_   256
#define H_   512
#define G4_  2048   // 4*H
#define V_   32000

// Output layout in d_out (floats): seq [64][512][512], h_last [64][512], mask [64][512]
#define OUT_SEQ   0
#define OUT_HLAST 16777216
#define OUT_MASK  16809984

// ws layout (bytes)
#define OFF_EMB  0u            // emb bf16 [32000][256]  = 16,384,000
#define OFF_WXT  16384000u     // WxT bf16 [2048][256]   =  1,048,576
#define OFF_WHT  17432576u     // WhT bf16 [2048][512]   =  2,097,152
#define OFF_H    19529728u     // hbuf bf16 [2][64][512] =    131,072
#define OFF_C    19660800u     // cbuf f32  [64][512]    =    131,072
#define OFF_CNT  19791872u     // counters int [4][512]  =      8,192
#define OFF_XZ   19800064u     // xz bf16 [TC][64][2048] = TC*262,144
#define XZ_PER_T 262144u

typedef short bf16x8 __attribute__((ext_vector_type(8)));
typedef float f32x4  __attribute__((ext_vector_type(4)));

__device__ __forceinline__ unsigned short f2bf(float f) {
  uint32_t u = __float_as_uint(f);
  u = (u + 0x7FFFu + ((u >> 16) & 1u)) >> 16;   // RNE
  return (unsigned short)u;
}
__device__ __forceinline__ float bf2f(unsigned short h) {
  return __uint_as_float(((uint32_t)h) << 16);
}
__device__ __forceinline__ float sigmoid_f(float x) { return 1.f / (1.f + __expf(-x)); }
__device__ __forceinline__ float tanh_f(float x) {
  x = fminf(fmaxf(x, -15.f), 15.f);
  float e = __expf(2.f * x);
  return (e - 1.f) / (e + 1.f);
}

// ---------- prep: cast embedding table to bf16 ----------
__global__ void k_prep_emb(const float* __restrict__ emb, unsigned short* __restrict__ out) {
  int i = (blockIdx.x * 256 + threadIdx.x) * 4;   // 8,192,000 elems total
  if (i < V_ * E_) {
    float4 v = *(const float4*)(emb + i);
    ushort4 o;
    o.x = f2bf(v.x); o.y = f2bf(v.y); o.z = f2bf(v.z); o.w = f2bf(v.w);
    *(ushort4*)(out + i) = o;
  }
}

// ---------- prep: WxT, WhT (transposed bf16 copies) + zero barrier counters ----------
__global__ void k_prep_w(const float* __restrict__ Wx, const float* __restrict__ Wh,
                         unsigned short* __restrict__ wxt, unsigned short* __restrict__ wht,
                         int* __restrict__ cnt) {
  int i = blockIdx.x * 256 + threadIdx.x;
  if (i < 524288) {                       // WxT[n][k] = Wx[k][n]
    int n = i >> 8, k = i & 255;
    wxt[i] = f2bf(Wx[k * G4_ + n]);
  } else if (i < 524288 + 1048576) {      // WhT[n][k] = Wh[k][n]
    int j = i - 524288;
    int n = j >> 9, k = j & 511;
    wht[j] = f2bf(Wh[k * G4_ + n]);
  } else if (i < 524288 + 1048576 + 2048) {
    cnt[i - (524288 + 1048576)] = 0;
  }
}

// ---------- mask output ----------
__global__ void k_mask(const int* __restrict__ seq, float* __restrict__ out) {
  int i = blockIdx.x * 256 + threadIdx.x;       // 32768
  if (i < B_ * T_) out[OUT_MASK + i] = (seq[i] != 0) ? 1.f : 0.f;
}

// ---------- h_last = seq[:, T-1, :] ----------
__global__ void k_hlast(const float* __restrict__ outseq, float* __restrict__ out) {
  int i = blockIdx.x * 256 + threadIdx.x;       // 32768
  if (i < B_ * H_)
    out[OUT_HLAST + i] = outseq[(size_t)(i >> 9) * (T_ * H_) + (size_t)(T_ - 1) * H_ + (i & 511)];
}

// ---------- phase 1: xz[m][n] = emb[seq][.]@Wx + b, m = (t-t0)*64 + b, bf16 out ----------
// tile 128x128, K=256 staged whole. 256 threads = 4 waves (2x2 of 64x64).
#define LDA_ 264   // 256 + 8 pad: row stride 528 B (16B-aligned, 2-way banks = free)
__global__ __launch_bounds__(256) void k_gemm_xz(
    const int* __restrict__ seq, const unsigned short* __restrict__ embb,
    const unsigned short* __restrict__ wxt, const float* __restrict__ bias,
    unsigned short* __restrict__ xz, int t0) {
  __shared__ __align__(16) unsigned short a_lds[128 * LDA_];
  __shared__ __align__(16) unsigned short b_lds[128 * LDA_];
  int bx = blockIdx.x & 15;     // N tile
  int by = blockIdx.x >> 4;     // M tile (chunk-local)
  int tid = threadIdx.x;

  { // stage A (gathered embedding rows) and B (WxT rows): 2 threads per 512B row
    int r = tid >> 1, half = tid & 1;
    int m = by * 128 + r;
    int t = t0 + (m >> 6), b = m & 63;
    int idx = seq[b * T_ + t];
    const unsigned short* srcA = embb + (size_t)idx * E_ + half * 128;
    const unsigned short* srcB = wxt + (size_t)(bx * 128 + r) * E_ + half * 128;
    unsigned short* dstA = a_lds + r * LDA_ + half * 128;
    unsigned short* dstB = b_lds + r * LDA_ + half * 128;
#pragma unroll
    for (int q = 0; q < 16; ++q) {
      *(bf16x8*)(dstA + q * 8) = *(const bf16x8*)(srcA + q * 8);
      *(bf16x8*)(dstB + q * 8) = *(const bf16x8*)(srcB + q * 8);
    }
  }
  __syncthreads();

  int w = tid >> 6, lane = tid & 63;
  int l15 = lane & 15, l4 = lane >> 4;
  int wm = w >> 1, wn = w & 1;
  f32x4 acc[4][4] = {};
#pragma unroll
  for (int ks = 0; ks < 8; ++ks) {
    bf16x8 a[4], bb[4];
#pragma unroll
    for (int mf = 0; mf < 4; ++mf)
      a[mf] = *(const bf16x8*)(a_lds + (wm * 64 + mf * 16 + l15) * LDA_ + ks * 32 + 8 * l4);
#pragma unroll
    for (int nf = 0; nf < 4; ++nf)
      bb[nf] = *(const bf16x8*)(b_lds + (wn * 64 + nf * 16 + l15) * LDA_ + ks * 32 + 8 * l4);
#pragma unroll
    for (int mf = 0; mf < 4; ++mf)
#pragma unroll
      for (int nf = 0; nf < 4; ++nf)
        acc[mf][nf] = __builtin_amdgcn_mfma_f32_16x16x32_bf16(a[mf], bb[nf], acc[mf][nf], 0, 0, 0);
  }
#pragma unroll
  for (int nf = 0; nf < 4; ++nf) {
    int n = bx * 128 + wn * 64 + nf * 16 + l15;
    float bv = bias[n];
#pragma unroll
    for (int mf = 0; mf < 4; ++mf)
#pragma unroll
      for (int q = 0; q < 4; ++q) {
        int m = by * 128 + wm * 64 + mf * 16 + l4 * 4 + q;
        xz[(size_t)m * G4_ + n] = f2bf(acc[mf][nf][q] + bv);
      }
  }
}

// ---------- phase 2: persistent LSTM recurrence ----------
// 64 blocks x 128 thr: group g = bid&3 (16 batches), slice n = bid>>2 (j in [32n,32n+32)).
// Wh^T slice resident in LDS: 128 cols (4 gates x 32 j) x 512 K.
#define LDW_ 520       // 512 + 8 pad (1040 B rows: 16B aligned, 2-way banks = free)
#define GRP_WG 16
__global__ __launch_bounds__(128) void k_lstm(
    const unsigned short* __restrict__ wht, const unsigned short* __restrict__ xz,
    unsigned short* __restrict__ hbuf, float* __restrict__ cbuf, int* __restrict__ cnt,
    float* __restrict__ outseq, int t0, int tend) {
  __shared__ __align__(16) unsigned short whl[128 * LDW_];  // [col c][k]
  __shared__ __align__(16) unsigned short hl[16 * LDW_];    // [batch][k]
  int bid = blockIdx.x;
  int g = bid & 3, n = bid >> 2;
  int J0 = n * 32;
  int tid = threadIdx.x;
  int w = tid >> 6, lane = tid & 63;
  int l15 = lane & 15, l4 = lane >> 4;
  int bglob0 = g * 16;
  int jcol = J0 + w * 16 + l15;          // this lane's j column (per gate)

  { // stage Wh^T slice: thread tid owns LDS col c=tid
    int c = tid, gt = c >> 5, jj = c & 31;
    const unsigned short* src = wht + (size_t)(gt * 512 + J0 + jj) * H_;
    unsigned short* dst = whl + c * LDW_;
    for (int q = 0; q < 64; ++q)
      *(bf16x8*)(dst + q * 8) = *(const bf16x8*)(src + q * 8);
  }

  float c4[4];
  if (t0 == 0) {
    c4[0] = c4[1] = c4[2] = c4[3] = 0.f;
  } else {
#pragma unroll
    for (int q = 0; q < 4; ++q) c4[q] = cbuf[(bglob0 + l4 * 4 + q) * H_ + jcol];
  }
  __syncthreads();

  for (int t = t0; t < tend; ++t) {
    // 1. stage h_{t-1} into LDS (zeros at t==0)
    if (t == 0) {
      for (int i = tid; i < 16 * LDW_ / 2; i += 128) ((uint32_t*)hl)[i] = 0u;
    } else {
      const unsigned short* hsrc = hbuf + (size_t)(t & 1) * (B_ * H_) + bglob0 * H_;
      int r = tid >> 3, part = tid & 7;
#pragma unroll
      for (int i = 0; i < 8; ++i) {
        int k = (part + i * 8) * 8;
        *(bf16x8*)(hl + r * LDW_ + k) = *(const bf16x8*)(hsrc + r * H_ + k);
      }
    }
    // 2. init acc from xz (z = xz + h@Wh)
    const unsigned short* xzt = xz + ((size_t)(t - t0) * B_ + bglob0) * G4_;
    f32x4 acc[4];
#pragma unroll
    for (int gt = 0; gt < 4; ++gt)
#pragma unroll
      for (int q = 0; q < 4; ++q)
        acc[gt][q] = bf2f(xzt[(l4 * 4 + q) * G4_ + gt * 512 + jcol]);
    __syncthreads();
    // 3. MFMA: 16 K-steps x 4 gates
#pragma unroll
    for (int ks = 0; ks < 16; ++ks) {
      bf16x8 a = *(const bf16x8*)(hl + l15 * LDW_ + ks * 32 + 8 * l4);
#pragma unroll
      for (int gt = 0; gt < 4; ++gt) {
        bf16x8 bb = *(const bf16x8*)(whl + (gt * 32 + w * 16 + l15) * LDW_ + ks * 32 + 8 * l4);
        acc[gt] = __builtin_amdgcn_mfma_f32_16x16x32_bf16(a, bb, acc[gt], 0, 0, 0);
      }
    }
    // 4-5. gates, state update, stores
    unsigned short* hdst = hbuf + (size_t)((t + 1) & 1) * (B_ * H_) + bglob0 * H_;
#pragma unroll
    for (int q = 0; q < 4; ++q) {
      float ig = sigmoid_f(acc[0][q]);
      float fg = sigmoid_f(acc[1][q]);
      float gg = tanh_f(acc[2][q]);
      float og = sigmoid_f(acc[3][q]);
      float cn = fg * c4[q] + ig * gg;
      c4[q] = cn;
      float hv = og * tanh_f(cn);
      int bl = l4 * 4 + q;
      hdst[bl * H_ + jcol] = f2bf(hv);
      outseq[(size_t)(bglob0 + bl) * (T_ * H_) + (size_t)t * H_ + jcol] = hv;
    }
    // 6. per-group barrier (skip after final step of chunk; kernel boundary syncs)
    if (t + 1 < tend) {
      __threadfence();
      __syncthreads();
      if (tid == 0)
        __hip_atomic_fetch_add(&cnt[g * T_ + t], 1, __ATOMIC_RELEASE, __HIP_MEMORY_SCOPE_AGENT);
      while (__hip_atomic_load(&cnt[g * T_ + t], __ATOMIC_ACQUIRE, __HIP_MEMORY_SCOPE_AGENT) < GRP_WG)
        __builtin_amdgcn_s_sleep(1);
      __syncthreads();
    }
  }
  // save c for next chunk
#pragma unroll
  for (int q = 0; q < 4; ++q) cbuf[(bglob0 + l4 * 4 + q) * H_ + jcol] = c4[q];
}

extern "C" void kernel_launch(void* const* d_in, const int* in_sizes, int n_in,
                              void* d_out, int out_size, void* d_ws, size_t ws_size,
                              hipStream_t stream) {
  const int* seq    = (const int*)d_in[0];
  const float* emb  = (const float*)d_in[1];
  const float* Wx   = (const float*)d_in[2];
  const float* Wh   = (const float*)d_in[3];
  const float* bias = (const float*)d_in[4];
  float* out = (float*)d_out;
  char* ws = (char*)d_ws;

  unsigned short* embb = (unsigned short*)(ws + OFF_EMB);
  unsigned short* wxt  = (unsigned short*)(ws + OFF_WXT);
  unsigned short* wht  = (unsigned short*)(ws + OFF_WHT);
  unsigned short* hbuf = (unsigned short*)(ws + OFF_H);
  float* cbuf          = (float*)(ws + OFF_C);
  int* cnt             = (int*)(ws + OFF_CNT);
  unsigned short* xz   = (unsigned short*)(ws + OFF_XZ);

  // chunk size: as many timesteps of xz as fit in ws (even, <= 512)
  size_t cap = (ws_size > OFF_XZ) ? (ws_size - OFF_XZ) : 0;
  int TC = (int)(cap / XZ_PER_T);
  if (TC > T_) TC = T_;
  TC &= ~1;
  if (TC < 2) TC = 2;   // requires ws_size >= ~20.3 MB

  k_prep_emb<<<dim3(8000), dim3(256), 0, stream>>>(emb, embb);
  k_prep_w<<<dim3(6152), dim3(256), 0, stream>>>(Wx, Wh, wxt, wht, cnt);
  k_mask<<<dim3(128), dim3(256), 0, stream>>>(seq, out);

  for (int t0 = 0; t0 < T_; t0 += TC) {
    int tc = T_ - t0; if (tc > TC) tc = TC;
    k_gemm_xz<<<dim3((tc / 2) * 16), dim3(256), 0, stream>>>(seq, embb, wxt, bias, xz, t0);
    k_lstm<<<dim3(64), dim3(128), 0, stream>>>(wht, xz, hbuf, cbuf, cnt, out, t0, t0 + tc);
  }
  k_hlast<<<dim3(128), dim3(256), 0, stream>>>(out, out);
}

// Round 2
// 3409.035 us; speedup vs baseline: 1.1969x; 1.1969x over previous
//
#include <hip/hip_runtime.h>
#include <stdint.h>

// Problem constants
#define B_   64
#define T_   512
#define E_   256
#define H_   512
#define G4_  2048   // 4*H
#define V_   32000

// Output layout in d_out (floats): seq [64][512][512], h_last [64][512], mask [64][512]
#define OUT_SEQ   0
#define OUT_HLAST 16777216
#define OUT_MASK  16809984

// ws layout (bytes)
#define OFF_EMB  0u            // emb bf16 [32000][256]  = 16,384,000
#define OFF_WXT  16384000u     // WxT bf16 [2048][256]   =  1,048,576
#define OFF_WHT  17432576u     // WhT bf16 [2048][512]   =  2,097,152
#define OFF_H    19529728u     // hbuf bf16 [2][64][512] =    131,072
#define OFF_C    19660800u     // cbuf f32  [64][512]    =    131,072
#define OFF_CNT  19791872u     // counters int [4][512]  =      8,192
#define OFF_XZ   19800064u     // xz bf16 [TC][64][2048] = TC*262,144
#define XZ_PER_T 262144u

typedef short bf16x8 __attribute__((ext_vector_type(8)));
typedef float f32x4  __attribute__((ext_vector_type(4)));

__device__ __forceinline__ unsigned short f2bf(float f) {
  uint32_t u = __float_as_uint(f);
  u = (u + 0x7FFFu + ((u >> 16) & 1u)) >> 16;   // RNE
  return (unsigned short)u;
}
__device__ __forceinline__ float bf2f(unsigned short h) {
  return __uint_as_float(((uint32_t)h) << 16);
}
__device__ __forceinline__ float sigmoid_f(float x) { return 1.f / (1.f + __expf(-x)); }
__device__ __forceinline__ float tanh_f(float x) {
  x = fminf(fmaxf(x, -15.f), 15.f);
  float e = __expf(2.f * x);
  return (e - 1.f) / (e + 1.f);
}

// ---------- prep: cast embedding table to bf16 ----------
__global__ void k_prep_emb(const float* __restrict__ emb, unsigned short* __restrict__ out) {
  int i = (blockIdx.x * 256 + threadIdx.x) * 4;   // 8,192,000 elems total
  if (i < V_ * E_) {
    float4 v = *(const float4*)(emb + i);
    ushort4 o;
    o.x = f2bf(v.x); o.y = f2bf(v.y); o.z = f2bf(v.z); o.w = f2bf(v.w);
    *(ushort4*)(out + i) = o;
  }
}

// ---------- prep: WxT, WhT (transposed bf16 copies) + zero barrier counters ----------
__global__ void k_prep_w(const float* __restrict__ Wx, const float* __restrict__ Wh,
                         unsigned short* __restrict__ wxt, unsigned short* __restrict__ wht,
                         int* __restrict__ cnt) {
  int i = blockIdx.x * 256 + threadIdx.x;
  if (i < 524288) {                       // WxT[n][k] = Wx[k][n]
    int n = i >> 8, k = i & 255;
    wxt[i] = f2bf(Wx[k * G4_ + n]);
  } else if (i < 524288 + 1048576) {      // WhT[n][k] = Wh[k][n]
    int j = i - 524288;
    int n = j >> 9, k = j & 511;
    wht[j] = f2bf(Wh[k * G4_ + n]);
  } else if (i < 524288 + 1048576 + 2048) {
    cnt[i - (524288 + 1048576)] = 0;
  }
}

// ---------- mask output ----------
__global__ void k_mask(const int* __restrict__ seq, float* __restrict__ out) {
  int i = blockIdx.x * 256 + threadIdx.x;       // 32768
  if (i < B_ * T_) out[OUT_MASK + i] = (seq[i] != 0) ? 1.f : 0.f;
}

// ---------- h_last = seq[:, T-1, :] ----------
__global__ void k_hlast(const float* __restrict__ outseq, float* __restrict__ out) {
  int i = blockIdx.x * 256 + threadIdx.x;       // 32768
  if (i < B_ * H_)
    out[OUT_HLAST + i] = outseq[(size_t)(i >> 9) * (T_ * H_) + (size_t)(T_ - 1) * H_ + (i & 511)];
}

// ---------- phase 1: xz[m][n] = emb[seq][.]@Wx + b, m = (t-t0)*64 + b, bf16 out ----------
#define LDA_ 264
__global__ __launch_bounds__(256) void k_gemm_xz(
    const int* __restrict__ seq, const unsigned short* __restrict__ embb,
    const unsigned short* __restrict__ wxt, const float* __restrict__ bias,
    unsigned short* __restrict__ xz, int t0) {
  __shared__ __align__(16) unsigned short a_lds[128 * LDA_];
  __shared__ __align__(16) unsigned short b_lds[128 * LDA_];
  int bx = blockIdx.x & 15;     // N tile
  int by = blockIdx.x >> 4;     // M tile (chunk-local)
  int tid = threadIdx.x;

  { // stage A (gathered embedding rows) and B (WxT rows): 2 threads per 512B row
    int r = tid >> 1, half = tid & 1;
    int m = by * 128 + r;
    int t = t0 + (m >> 6), b = m & 63;
    int idx = seq[b * T_ + t];
    const unsigned short* srcA = embb + (size_t)idx * E_ + half * 128;
    const unsigned short* srcB = wxt + (size_t)(bx * 128 + r) * E_ + half * 128;
    unsigned short* dstA = a_lds + r * LDA_ + half * 128;
    unsigned short* dstB = b_lds + r * LDA_ + half * 128;
#pragma unroll
    for (int q = 0; q < 16; ++q) {
      *(bf16x8*)(dstA + q * 8) = *(const bf16x8*)(srcA + q * 8);
      *(bf16x8*)(dstB + q * 8) = *(const bf16x8*)(srcB + q * 8);
    }
  }
  __syncthreads();

  int w = tid >> 6, lane = tid & 63;
  int l15 = lane & 15, l4 = lane >> 4;
  int wm = w >> 1, wn = w & 1;
  f32x4 acc[4][4] = {};
#pragma unroll
  for (int ks = 0; ks < 8; ++ks) {
    bf16x8 a[4], bb[4];
#pragma unroll
    for (int mf = 0; mf < 4; ++mf)
      a[mf] = *(const bf16x8*)(a_lds + (wm * 64 + mf * 16 + l15) * LDA_ + ks * 32 + 8 * l4);
#pragma unroll
    for (int nf = 0; nf < 4; ++nf)
      bb[nf] = *(const bf16x8*)(b_lds + (wn * 64 + nf * 16 + l15) * LDA_ + ks * 32 + 8 * l4);
#pragma unroll
    for (int mf = 0; mf < 4; ++mf)
#pragma unroll
      for (int nf = 0; nf < 4; ++nf)
        acc[mf][nf] = __builtin_amdgcn_mfma_f32_16x16x32_bf16(a[mf], bb[nf], acc[mf][nf], 0, 0, 0);
  }
#pragma unroll
  for (int nf = 0; nf < 4; ++nf) {
    int n = bx * 128 + wn * 64 + nf * 16 + l15;
    float bv = bias[n];
#pragma unroll
    for (int mf = 0; mf < 4; ++mf)
#pragma unroll
      for (int q = 0; q < 4; ++q) {
        int m = by * 128 + wm * 64 + mf * 16 + l4 * 4 + q;
        xz[(size_t)m * G4_ + n] = f2bf(acc[mf][nf][q] + bv);
      }
  }
}

// ---------- phase 2: persistent LSTM recurrence ----------
// 64 blocks x 128 thr (2 waves): group g = bid&3 (16 batches), WG covers j in
// [32*(bid>>2), +32); wave w covers 16 j-cols x 4 gates. Wh^T fragments live in
// REGISTERS (64 frags x 4 VGPR = 256 VGPR) -- no LDS in the loop.
// h exchange: device-scope relaxed atomic u64 stores (write-through, sc1) +
// hand-placed vmcnt(0) + relaxed flag add; consumers poll relaxed and read h
// straight from the coherence point as relaxed atomic u64 loads. No fences,
// no buffer_wbl2/buffer_inv anywhere in the loop.
#define GRP_WG 16
__global__ __launch_bounds__(128, 1) void k_lstm(
    const unsigned short* __restrict__ wht, const unsigned short* __restrict__ xz,
    unsigned long long* hbuf, float* cbuf, int* cnt,
    float* __restrict__ outseq, int t0, int tend) {
  int bid = blockIdx.x;
  int g = bid & 3, nwg = bid >> 2;
  int J0 = nwg * 32;
  int tid = threadIdx.x;
  int w = tid >> 6, lane = tid & 63;
  int l15 = lane & 15, l4 = lane >> 4;
  int bglob0 = g * 16;
  int jcol = J0 + w * 16 + l15;          // this lane's j column (per gate)

  // B fragments resident in registers: Bf[gt][ks] = WhT[gt*512+jcol][ks*32+l4*8 .. +7]
  bf16x8 Bf[4][16];
#pragma unroll
  for (int gt = 0; gt < 4; ++gt)
#pragma unroll
    for (int ks = 0; ks < 16; ++ks)
      Bf[gt][ks] = *(const bf16x8*)(wht + (size_t)(gt * 512 + jcol) * H_ + ks * 32 + l4 * 8);

  float c4[4];
  if (t0 == 0) {
    c4[0] = c4[1] = c4[2] = c4[3] = 0.f;
  } else {
#pragma unroll
    for (int q = 0; q < 4; ++q) c4[q] = cbuf[(bglob0 + l4 * 4 + q) * H_ + jcol];
  }

  for (int t = t0; t < tend; ++t) {
    // acc init from xz (independent of h -> issued before the poll)
    const unsigned short* xzt = xz + ((size_t)(t - t0) * B_ + bglob0) * G4_;
    f32x4 acc[4];
#pragma unroll
    for (int gt = 0; gt < 4; ++gt)
#pragma unroll
      for (int q = 0; q < 4; ++q)
        acc[gt][q] = bf2f(xzt[(l4 * 4 + q) * G4_ + gt * 512 + jcol]);

    if (t > 0) {
      // wait for all 16 WGs' h_{t-1} slices
      while (__hip_atomic_load(&cnt[g * T_ + (t - 1)], __ATOMIC_RELAXED, __HIP_MEMORY_SCOPE_AGENT) < GRP_WG)
        __builtin_amdgcn_s_sleep(1);
      asm volatile("" ::: "memory");
      // A-frags straight from the coherence point (no LDS): h[bglob0+l15][ks*32+l4*8 ..]
      const unsigned long long* hsrc = hbuf + (size_t)((t - 1) & 1) * (B_ * H_ / 4);
      bf16x8 Af[16];
#pragma unroll
      for (int ks = 0; ks < 16; ++ks) {
        int base = (bglob0 + l15) * (H_ / 4) + ks * 8 + l4 * 2;
        unsigned long long lo = __hip_atomic_load(hsrc + base,     __ATOMIC_RELAXED, __HIP_MEMORY_SCOPE_AGENT);
        unsigned long long hi = __hip_atomic_load(hsrc + base + 1, __ATOMIC_RELAXED, __HIP_MEMORY_SCOPE_AGENT);
        union { unsigned long long u[2]; bf16x8 v; } cv;
        cv.u[0] = lo; cv.u[1] = hi;
        Af[ks] = cv.v;
      }
#pragma unroll
      for (int ks = 0; ks < 16; ++ks)
#pragma unroll
        for (int gt = 0; gt < 4; ++gt)
          acc[gt] = __builtin_amdgcn_mfma_f32_16x16x32_bf16(Af[ks], Bf[gt][ks], acc[gt], 0, 0, 0);
    }

    // gates + state update
    float hvf[4];
#pragma unroll
    for (int q = 0; q < 4; ++q) {
      float ig = sigmoid_f(acc[0][q]);
      float fg = sigmoid_f(acc[1][q]);
      float gg = tanh_f(acc[2][q]);
      float og = sigmoid_f(acc[3][q]);
      float cn = fg * c4[q] + ig * gg;
      c4[q] = cn;
      hvf[q] = og * tanh_f(cn);
    }

    // publish h_t: pack cols jcol..jcol+3 (4 lanes) into u64, store write-through
    unsigned long long* hdst = hbuf + (size_t)(t & 1) * (B_ * H_ / 4);
#pragma unroll
    for (int q = 0; q < 4; ++q) {
      unsigned int my = f2bf(hvf[q]);
      unsigned int p1 = __shfl_xor(my, 1);
      unsigned int pair = my | (p1 << 16);        // cols j, j+1 (valid on even l15)
      unsigned int hi2 = __shfl_xor(pair, 2);     // cols j+2, j+3 (valid on l15%4==0)
      if ((l15 & 3) == 0) {
        unsigned long long v = (unsigned long long)pair | ((unsigned long long)hi2 << 32);
        __hip_atomic_store(&hdst[(bglob0 + l4 * 4 + q) * (H_ / 4) + (jcol >> 2)], v,
                           __ATOMIC_RELAXED, __HIP_MEMORY_SCOPE_AGENT);
      }
    }
    asm volatile("s_waitcnt vmcnt(0)" ::: "memory");
    __syncthreads();                               // both waves' stores drained
    if (tid == 0)
      __hip_atomic_fetch_add(&cnt[g * T_ + t], 1, __ATOMIC_RELAXED, __HIP_MEMORY_SCOPE_AGENT);

    // seq output (normal cached stores, after the flag -- off critical path)
#pragma unroll
    for (int q = 0; q < 4; ++q)
      outseq[(size_t)(bglob0 + l4 * 4 + q) * (T_ * H_) + (size_t)t * H_ + jcol] = hvf[q];
  }

  // save c for next chunk
#pragma unroll
  for (int q = 0; q < 4; ++q) cbuf[(bglob0 + l4 * 4 + q) * H_ + jcol] = c4[q];
}

extern "C" void kernel_launch(void* const* d_in, const int* in_sizes, int n_in,
                              void* d_out, int out_size, void* d_ws, size_t ws_size,
                              hipStream_t stream) {
  const int* seq    = (const int*)d_in[0];
  const float* emb  = (const float*)d_in[1];
  const float* Wx   = (const float*)d_in[2];
  const float* Wh   = (const float*)d_in[3];
  const float* bias = (const float*)d_in[4];
  float* out = (float*)d_out;
  char* ws = (char*)d_ws;

  unsigned short* embb = (unsigned short*)(ws + OFF_EMB);
  unsigned short* wxt  = (unsigned short*)(ws + OFF_WXT);
  unsigned short* wht  = (unsigned short*)(ws + OFF_WHT);
  unsigned long long* hbuf = (unsigned long long*)(ws + OFF_H);
  float* cbuf          = (float*)(ws + OFF_C);
  int* cnt             = (int*)(ws + OFF_CNT);
  unsigned short* xz   = (unsigned short*)(ws + OFF_XZ);

  // chunk size: as many timesteps of xz as fit in ws (even, <= 512)
  size_t cap = (ws_size > OFF_XZ) ? (ws_size - OFF_XZ) : 0;
  int TC = (int)(cap / XZ_PER_T);
  if (TC > T_) TC = T_;
  TC &= ~1;
  if (TC < 2) TC = 2;   // requires ws_size >= ~20.3 MB

  k_prep_emb<<<dim3(8000), dim3(256), 0, stream>>>(emb, embb);
  k_prep_w<<<dim3(6152), dim3(256), 0, stream>>>(Wx, Wh, wxt, wht, cnt);
  k_mask<<<dim3(128), dim3(256), 0, stream>>>(seq, out);

  for (int t0 = 0; t0 < T_; t0 += TC) {
    int tc = T_ - t0; if (tc > TC) tc = TC;
    k_gemm_xz<<<dim3((tc / 2) * 16), dim3(256), 0, stream>>>(seq, embb, wxt, bias, xz, t0);
    k_lstm<<<dim3(64), dim3(128), 0, stream>>>(wht, xz, hbuf, cbuf, cnt, out, t0, t0 + tc);
  }
  k_hlast<<<dim3(128), dim3(256), 0, stream>>>(out, out);
}

// Round 3
// 2624.215 us; speedup vs baseline: 1.5548x; 1.2991x over previous
//
#include <hip/hip_runtime.h>
#include <stdint.h>

// Problem constants
#define B_   64
#define T_   512
#define E_   256
#define H_   512
#define G4_  2048   // 4*H
#define V_   32000

// Output layout in d_out (floats): seq [64][512][512], h_last [64][512], mask [64][512]
#define OUT_SEQ   0
#define OUT_HLAST 16777216
#define OUT_MASK  16809984

// ws layout (bytes)
#define OFF_EMB  0u            // emb bf16 [32000][256]  = 16,384,000
#define OFF_WXT  16384000u     // WxT bf16 [2048][256]   =  1,048,576
#define OFF_WHT  17432576u     // WhT bf16 [2048][512]   =  2,097,152
#define OFF_C    19529728u     // cbuf f32  [64][512]    =    131,072
#define OFF_XZ   19660800u     // xz bf16 [TC][64][2048] = TC*262,144, then h-ring
#define XZ_PER_T   262144u
#define RING_PER_T  65536u     // one h slot: [64][512] bf16
#define SLOT_U64    8192       // 65536 / 8

#define POISON64 0xFFFFFFFFFFFFFFFFULL

typedef short bf16x8 __attribute__((ext_vector_type(8)));
typedef float f32x4  __attribute__((ext_vector_type(4)));
typedef unsigned int u32x4 __attribute__((ext_vector_type(4)));

__device__ __forceinline__ unsigned short f2bf(float f) {
  uint32_t u = __float_as_uint(f);
  u = (u + 0x7FFFu + ((u >> 16) & 1u)) >> 16;   // RNE
  return (unsigned short)u;
}
__device__ __forceinline__ float bf2f(unsigned short h) {
  return __uint_as_float(((uint32_t)h) << 16);
}
__device__ __forceinline__ float sigmoid_f(float x) { return 1.f / (1.f + __expf(-x)); }
__device__ __forceinline__ float tanh_f(float x) {
  x = fminf(fmaxf(x, -15.f), 15.f);
  float e = __expf(2.f * x);
  return (e - 1.f) / (e + 1.f);
}

// ---------- prep: cast embedding table to bf16 ----------
__global__ void k_prep_emb(const float* __restrict__ emb, unsigned short* __restrict__ out) {
  int i = (blockIdx.x * 256 + threadIdx.x) * 4;   // 8,192,000 elems total
  if (i < V_ * E_) {
    float4 v = *(const float4*)(emb + i);
    ushort4 o;
    o.x = f2bf(v.x); o.y = f2bf(v.y); o.z = f2bf(v.z); o.w = f2bf(v.w);
    *(ushort4*)(out + i) = o;
  }
}

// ---------- prep: WxT, WhT (transposed bf16 copies) ----------
__global__ void k_prep_w(const float* __restrict__ Wx, const float* __restrict__ Wh,
                         unsigned short* __restrict__ wxt, unsigned short* __restrict__ wht) {
  int i = blockIdx.x * 256 + threadIdx.x;
  if (i < 524288) {                       // WxT[n][k] = Wx[k][n]
    int n = i >> 8, k = i & 255;
    wxt[i] = f2bf(Wx[k * G4_ + n]);
  } else if (i < 524288 + 1048576) {      // WhT[n][k] = Wh[k][n]
    int j = i - 524288;
    int n = j >> 9, k = j & 511;
    wht[j] = f2bf(Wh[k * G4_ + n]);
  }
}

// ---------- mask output ----------
__global__ void k_mask(const int* __restrict__ seq, float* __restrict__ out) {
  int i = blockIdx.x * 256 + threadIdx.x;       // 32768
  if (i < B_ * T_) out[OUT_MASK + i] = (seq[i] != 0) ? 1.f : 0.f;
}

// ---------- h_last = seq[:, T-1, :] ----------
__global__ void k_hlast(const float* __restrict__ outseq, float* __restrict__ out) {
  int i = blockIdx.x * 256 + threadIdx.x;       // 32768
  if (i < B_ * H_)
    out[OUT_HLAST + i] = outseq[(size_t)(i >> 9) * (T_ * H_) + (size_t)(T_ - 1) * H_ + (i & 511)];
}

// ---------- phase 1: xz[m][n] = emb[seq][.]@Wx + b, m = (t-t0)*64 + b, bf16 out ----------
#define LDA_ 264
__global__ __launch_bounds__(256) void k_gemm_xz(
    const int* __restrict__ seq, const unsigned short* __restrict__ embb,
    const unsigned short* __restrict__ wxt, const float* __restrict__ bias,
    unsigned short* __restrict__ xz, int t0) {
  __shared__ __align__(16) unsigned short a_lds[128 * LDA_];
  __shared__ __align__(16) unsigned short b_lds[128 * LDA_];
  int bx = blockIdx.x & 15;     // N tile
  int by = blockIdx.x >> 4;     // M tile (chunk-local)
  int tid = threadIdx.x;

  { // stage A (gathered embedding rows) and B (WxT rows): 2 threads per 512B row
    int r = tid >> 1, half = tid & 1;
    int m = by * 128 + r;
    int t = t0 + (m >> 6), b = m & 63;
    int idx = seq[b * T_ + t];
    const unsigned short* srcA = embb + (size_t)idx * E_ + half * 128;
    const unsigned short* srcB = wxt + (size_t)(bx * 128 + r) * E_ + half * 128;
    unsigned short* dstA = a_lds + r * LDA_ + half * 128;
    unsigned short* dstB = b_lds + r * LDA_ + half * 128;
#pragma unroll
    for (int q = 0; q < 16; ++q) {
      *(bf16x8*)(dstA + q * 8) = *(const bf16x8*)(srcA + q * 8);
      *(bf16x8*)(dstB + q * 8) = *(const bf16x8*)(srcB + q * 8);
    }
  }
  __syncthreads();

  int w = tid >> 6, lane = tid & 63;
  int l15 = lane & 15, l4 = lane >> 4;
  int wm = w >> 1, wn = w & 1;
  f32x4 acc[4][4] = {};
#pragma unroll
  for (int ks = 0; ks < 8; ++ks) {
    bf16x8 a[4], bb[4];
#pragma unroll
    for (int mf = 0; mf < 4; ++mf)
      a[mf] = *(const bf16x8*)(a_lds + (wm * 64 + mf * 16 + l15) * LDA_ + ks * 32 + 8 * l4);
#pragma unroll
    for (int nf = 0; nf < 4; ++nf)
      bb[nf] = *(const bf16x8*)(b_lds + (wn * 64 + nf * 16 + l15) * LDA_ + ks * 32 + 8 * l4);
#pragma unroll
    for (int mf = 0; mf < 4; ++mf)
#pragma unroll
      for (int nf = 0; nf < 4; ++nf)
        acc[mf][nf] = __builtin_amdgcn_mfma_f32_16x16x32_bf16(a[mf], bb[nf], acc[mf][nf], 0, 0, 0);
  }
#pragma unroll
  for (int nf = 0; nf < 4; ++nf) {
    int n = bx * 128 + wn * 64 + nf * 16 + l15;
    float bv = bias[n];
#pragma unroll
    for (int mf = 0; mf < 4; ++mf)
#pragma unroll
      for (int q = 0; q < 4; ++q) {
        int m = by * 128 + wm * 64 + mf * 16 + l4 * 4 + q;
        xz[(size_t)m * G4_ + n] = f2bf(acc[mf][nf][q] + bv);
      }
  }
}

// ---------- phase 2: persistent LSTM recurrence ----------
// 64 WGs x 128 thr (2 waves): group g = bid&3 (16 batches), WG owns j-slice
// [32*(bid>>2), +32); wave w covers 16 j-cols x 4 gates.
// Weights: Wh^T fragments PINNED in VGPRs via identity asm (defeats remat).
// h exchange: depth-(R) ring of 64KB slots, poisoned 0xFF per chunk. Producers
// fire-and-forget relaxed u64 atomic stores; consumers poll the data u64s for
// non-poison (|h|<=1 so a packed value can never be all-0xFFFF). No flags, no
// fences, no vmcnt drains, no __syncthreads anywhere in the loop.
__global__ __launch_bounds__(128, 1) void k_lstm(
    const unsigned short* __restrict__ wht, const unsigned short* __restrict__ xz,
    unsigned long long* hring, float* cbuf,
    float* __restrict__ outseq, int t0, int tend, int R) {
  int bid = blockIdx.x;
  int g = bid & 3, nwg = bid >> 2;
  int J0 = nwg * 32;
  int tid = threadIdx.x;
  int w = tid >> 6, lane = tid & 63;
  int l15 = lane & 15, l4 = lane >> 4;
  int bglob0 = g * 16;
  int jcol = J0 + w * 16 + l15;          // this lane's j column (per gate)

  // B fragments in registers, PINNED: Bs[gt][ks] = WhT[gt*512+jcol][ks*32+l4*8 .. +7]
  u32x4 Bs[4][16];
#pragma unroll
  for (int gt = 0; gt < 4; ++gt)
#pragma unroll
    for (int ks = 0; ks < 16; ++ks) {
      Bs[gt][ks] = *(const u32x4*)(wht + (size_t)(gt * 512 + jcol) * H_ + ks * 32 + l4 * 8);
      asm volatile("" : "+v"(Bs[gt][ks]));   // value now asm-defined: cannot be remat'd as a load
    }

  float c4[4];
  if (t0 == 0) {
    c4[0] = c4[1] = c4[2] = c4[3] = 0.f;
  } else {
#pragma unroll
    for (int q = 0; q < 4; ++q) c4[q] = cbuf[(bglob0 + l4 * 4 + q) * H_ + jcol];
  }

  int abase = (bglob0 + l15) * (H_ / 4) + l4 * 2;   // u64 index of this lane's A-frag base

  for (int t = t0; t < tend; ++t) {
    // acc init from xz (independent of h -> issued before the poll)
    const unsigned short* xzt = xz + ((size_t)(t - t0) * B_ + bglob0) * G4_;
    f32x4 acc[4];
#pragma unroll
    for (int gt = 0; gt < 4; ++gt)
#pragma unroll
      for (int q = 0; q < 4; ++q)
        acc[gt][q] = bf2f(xzt[(l4 * 4 + q) * G4_ + gt * 512 + jcol]);

    if (t > 0) {
      const unsigned long long* hsrc = hring + (size_t)((t - 1) % R) * SLOT_U64;
      unsigned long long v[32];
      // self-validating poll: reload until every u64 is non-poison
      while (true) {
        bool ok = true;
#pragma unroll
        for (int ks = 0; ks < 16; ++ks) {
          v[2 * ks]     = __hip_atomic_load(hsrc + abase + ks * 8,     __ATOMIC_RELAXED, __HIP_MEMORY_SCOPE_AGENT);
          v[2 * ks + 1] = __hip_atomic_load(hsrc + abase + ks * 8 + 1, __ATOMIC_RELAXED, __HIP_MEMORY_SCOPE_AGENT);
        }
#pragma unroll
        for (int i = 0; i < 32; ++i) ok &= (v[i] != POISON64);
        if (__all(ok)) break;
      }
#pragma unroll
      for (int ks = 0; ks < 16; ++ks) {
        union { unsigned long long u[2]; bf16x8 b; } cv;
        cv.u[0] = v[2 * ks]; cv.u[1] = v[2 * ks + 1];
#pragma unroll
        for (int gt = 0; gt < 4; ++gt)
          acc[gt] = __builtin_amdgcn_mfma_f32_16x16x32_bf16(
              cv.b, __builtin_bit_cast(bf16x8, Bs[gt][ks]), acc[gt], 0, 0, 0);
      }
    }

    // gates + state update
    float hvf[4];
#pragma unroll
    for (int q = 0; q < 4; ++q) {
      float ig = sigmoid_f(acc[0][q]);
      float fg = sigmoid_f(acc[1][q]);
      float gg = tanh_f(acc[2][q]);
      float og = sigmoid_f(acc[3][q]);
      float cn = fg * c4[q] + ig * gg;
      c4[q] = cn;
      hvf[q] = og * tanh_f(cn);
    }

    // publish h_t: pack cols jcol..jcol+3 (4 lanes) into u64, fire-and-forget
    unsigned long long* hdst = hring + (size_t)(t % R) * SLOT_U64;
#pragma unroll
    for (int q = 0; q < 4; ++q) {
      unsigned int my = f2bf(hvf[q]);
      unsigned int p1 = __shfl_xor(my, 1);
      unsigned int pair = my | (p1 << 16);        // cols j, j+1 (valid on even l15)
      unsigned int hi2 = __shfl_xor(pair, 2);     // cols j+2, j+3 (valid on l15%4==0)
      if ((l15 & 3) == 0) {
        unsigned long long vv = (unsigned long long)pair | ((unsigned long long)hi2 << 32);
        __hip_atomic_store(&hdst[(bglob0 + l4 * 4 + q) * (H_ / 4) + (jcol >> 2)], vv,
                           __ATOMIC_RELAXED, __HIP_MEMORY_SCOPE_AGENT);
      }
    }

    // seq output (normal cached stores, off critical path)
#pragma unroll
    for (int q = 0; q < 4; ++q)
      outseq[(size_t)(bglob0 + l4 * 4 + q) * (T_ * H_) + (size_t)t * H_ + jcol] = hvf[q];
  }

  // save c for next chunk
#pragma unroll
  for (int q = 0; q < 4; ++q) cbuf[(bglob0 + l4 * 4 + q) * H_ + jcol] = c4[q];
}

extern "C" void kernel_launch(void* const* d_in, const int* in_sizes, int n_in,
                              void* d_out, int out_size, void* d_ws, size_t ws_size,
                              hipStream_t stream) {
  const int* seq    = (const int*)d_in[0];
  const float* emb  = (const float*)d_in[1];
  const float* Wx   = (const float*)d_in[2];
  const float* Wh   = (const float*)d_in[3];
  const float* bias = (const float*)d_in[4];
  float* out = (float*)d_out;
  char* ws = (char*)d_ws;

  unsigned short* embb = (unsigned short*)(ws + OFF_EMB);
  unsigned short* wxt  = (unsigned short*)(ws + OFF_WXT);
  unsigned short* wht  = (unsigned short*)(ws + OFF_WHT);
  float* cbuf          = (float*)(ws + OFF_C);
  unsigned short* xz   = (unsigned short*)(ws + OFF_XZ);

  // chunk size: xz (TC slots) + h-ring (TC+1 slots) must fit after OFF_XZ
  size_t cap = (ws_size > OFF_XZ) ? (ws_size - OFF_XZ) : 0;
  int TC = (cap > RING_PER_T) ? (int)((cap - RING_PER_T) / (XZ_PER_T + RING_PER_T)) : 2;
  if (TC > T_) TC = T_;
  TC &= ~1;
  if (TC < 2) TC = 2;   // requires ws_size >= ~20.4 MB
  int R = TC + 1;
  unsigned long long* hring = (unsigned long long*)(ws + OFF_XZ + (size_t)TC * XZ_PER_T);

  k_prep_emb<<<dim3(8000), dim3(256), 0, stream>>>(emb, embb);
  k_prep_w<<<dim3(6144), dim3(256), 0, stream>>>(Wx, Wh, wxt, wht);
  k_mask<<<dim3(128), dim3(256), 0, stream>>>(seq, out);

  for (int t0 = 0; t0 < T_; t0 += TC) {
    int tc = T_ - t0; if (tc > TC) tc = TC;
    // poison the tc ring slots this chunk will write: [t0 % R, +tc) mod R.
    // Slot (t0-1)%R (h carried from previous chunk) is never in this range.
    int s0 = t0 % R;
    if (s0 + tc <= R) {
      hipMemsetAsync((char*)hring + (size_t)s0 * RING_PER_T, 0xFF, (size_t)tc * RING_PER_T, stream);
    } else {
      hipMemsetAsync((char*)hring + (size_t)s0 * RING_PER_T, 0xFF, (size_t)(R - s0) * RING_PER_T, stream);
      hipMemsetAsync((char*)hring, 0xFF, (size_t)(s0 + tc - R) * RING_PER_T, stream);
    }
    k_gemm_xz<<<dim3((tc / 2) * 16), dim3(256), 0, stream>>>(seq, embb, wxt, bias, xz, t0);
    k_lstm<<<dim3(64), dim3(128), 0, stream>>>(wht, xz, hring, cbuf, out, t0, t0 + tc, R);
  }
  k_hlast<<<dim3(128), dim3(256), 0, stream>>>(out, out);
}